// Round 1
// baseline (56.226 us; speedup 1.0000x reference)
//
#include <hip/hip_runtime.h>

// Closed form derived from the circuit algebra:
//   state = ⊗_i RY(p_i) RX(x_i) |0>   (product state; gates act on disjoint wires)
//   CNOT ladder in Heisenberg picture: U† Z_i U = Z_0 Z_1 ... Z_i
//   <Z>_single(α, β) = cos(α) cos(β)  for RY(β)RX(α)|0>
//   => out[b,i] = prod_{j<=i} cos(x[b,j]) * cos(params[j])
//              = (prefix-prod cos x) * (prefix-prod cos p)   [p-part uniform]
//
// Inputs are N(0,1) (|arg| < ~6), so the hardware v_cos_f32 path (__cosf)
// is accurate to ~1e-6 here — ample slack vs the absmax threshold.
//
// Iteration-time structure (rocprof): the timed graph is dominated by the
// harness's 256 MiB workspace-poison fill (~41 µs @ 82% HBM peak — at the
// achievable fill ceiling). This kernel is the only controllable slice
// (~3-6 µs incl. dispatch). Layout below makes staging exactly uniform:
// 2 rows/thread -> 320 vec4/block = 5 float4 ops/thread, no masked tail.

#define NQ   10
#define BLK  64
#define ROWS_PER_THREAD 2
#define ROWS_PER_BLK   (BLK * ROWS_PER_THREAD)   // 128
#define FLOATS_PER_BLK (ROWS_PER_BLK * NQ)       // 1280
#define VEC4_PER_BLK   (FLOATS_PER_BLK / 4)      // 320 = 5 * BLK (exact)

__global__ __launch_bounds__(BLK)
void qsim_prefix_kernel(const float4* __restrict__ x4,
                        const float* __restrict__ p,
                        float4* __restrict__ out4,
                        int total_vec4) {
    __shared__ float sx[FLOATS_PER_BLK];   // unpadded: float4-contiguous
    float4* sx4 = (float4*)sx;
    const int t = threadIdx.x;
    const int vbase = blockIdx.x * VEC4_PER_BLK;

    // Uniform prefix product of cos(params): 10 broadcast scalar loads
    // (scalar-cached), 10 v_cos + 9 v_mul, hoisted out of the row loop.
    float cpp[NQ];
    {
        float accp = 1.0f;
#pragma unroll
        for (int j = 0; j < NQ; ++j) { accp *= __cosf(p[j]); cpp[j] = accp; }
    }

    // Coalesced float4 global -> LDS: exactly 5 full-wave iterations.
#pragma unroll
    for (int k = 0; k < 5; ++k) {
        int idx = k * BLK + t;
        if (vbase + idx < total_vec4)
            sx4[idx] = x4[vbase + idx];
    }
    __syncthreads();

    // Thread t owns rows 2t and 2t+1 (floats [row*10, row*10+10)).
    // Prefix product with hardware cosine; in-place overwrite of own rows
    // only -> no cross-thread hazard.
#pragma unroll
    for (int r = 0; r < ROWS_PER_THREAD; ++r) {
        const int row = t * ROWS_PER_THREAD + r;
        float acc = 1.0f;
#pragma unroll
        for (int j = 0; j < NQ; ++j) {
            acc *= __cosf(sx[row * NQ + j]);
            sx[row * NQ + j] = acc * cpp[j];
        }
    }
    __syncthreads();

    // Coalesced LDS -> global float4 store: exactly 5 full-wave iterations.
#pragma unroll
    for (int k = 0; k < 5; ++k) {
        int idx = k * BLK + t;
        if (vbase + idx < total_vec4)
            out4[vbase + idx] = sx4[idx];
    }
}

extern "C" void kernel_launch(void* const* d_in, const int* in_sizes, int n_in,
                              void* d_out, int out_size, void* d_ws, size_t ws_size,
                              hipStream_t stream) {
    const float4* x4 = (const float4*)d_in[0];  // [BATCH, NQ] float32
    const float* p = (const float*)d_in[1];     // [NQ] float32
    float4* out4 = (float4*)d_out;              // [BATCH, NQ] float32

    const int total = in_sizes[0];              // BATCH * NQ = 163840
    const int batch = total / NQ;               // 16384
    const int grid = (batch + ROWS_PER_BLK - 1) / ROWS_PER_BLK;  // 128

    qsim_prefix_kernel<<<grid, BLK, 0, stream>>>(x4, p, out4, total / 4);
}